// Round 5
// baseline (329.194 us; speedup 1.0000x reference)
//
#include <hip/hip_runtime.h>
#include <hip/hip_bf16.h>
#include <math.h>

#define B_N 4096
#define M_N 128
#define F_N 32
#define H_N 512
#define NFM 4096   // F*M

// wave-local LDS sync: all lanes of a wave run in lockstep, so a waitcnt on
// outstanding LDS ops makes prior cross-lane LDS writes visible to reads.
#define WAVE_SYNC() do { \
  asm volatile("s_waitcnt lgkmcnt(0)" ::: "memory"); \
  __builtin_amdgcn_sched_barrier(0); \
} while (0)

// ---------------------------------------------------------------------------
// Kernel 1: occupied-index extraction (wave ballot, parallel) + hidden layer
//   h[b,:] = tanhf( sum_j W1[idx_j,:] + b1 )   (ascending-j chain, fp32)
// ---------------------------------------------------------------------------
__global__ __launch_bounds__(256) void k1_idx_h(
    const float* __restrict__ n, const float* __restrict__ W1,
    const float* __restrict__ b1, float* __restrict__ h_ws,
    int* __restrict__ idx_ws)
{
  __shared__ int s_idx[F_N];
  __shared__ int s_cnt0;
  const int b = blockIdx.x;
  const int t = threadIdx.x;

  bool p = false;
  int before = 0;
  if (t < 128) {
    float v = n[(size_t)b * M_N + t];
    p = v > 0.5f;
    unsigned long long m = __ballot(p);
    int lane = t & 63;
    before = __popcll(m & ((1ull << lane) - 1ull));
    if (t < 64) {
      if (lane == 0) s_cnt0 = __popcll(m);
      if (p) s_idx[before] = t;          // ascending within wave 0
    }
  }
  __syncthreads();
  if (t >= 64 && t < 128 && p) s_idx[s_cnt0 + before] = t;
  __syncthreads();

  if (t < F_N) idx_ws[b * F_N + t] = s_idx[t];

  #pragma unroll
  for (int cc = 0; cc < 2; ++cc) {
    int c = t + cc * 256;
    float acc = 0.0f;
    #pragma unroll
    for (int j = 0; j < F_N; ++j)
      acc += W1[(size_t)s_idx[j] * H_N + c];
    acc += b1[c];                        // b1 = zeros: exact
    h_ws[(size_t)b * H_N + c] = tanhf(acc);
  }
}

// ---------------------------------------------------------------------------
// Kernel 2 (ROUND 16): tiled fp32 GEMM  bf = h @ W2.
// POST-MORTEM rounds 0/2/4: every config ran exactly 8 waves/CU (2/SIMD) —
//   r0: grid 512 = 2 blk/CU x 4 waves; r2: grid 512 = 2 blk/CU (LDS allowed
//   3, grid didn't); r4: 4 blk/CU x 2 waves. All pinned at VALUBusy ~60%,
//   k2 225-237 us. At 2 waves/SIMD the per-kk LDS-read latency + per-tile
//   barrier drains leave ~40% of issue slots idle. The limiter is LATENCY
//   HIDING, not LDS bandwidth (a-frags are broadcast reads).
// ROUND 16: first config with 16 waves/CU: 128x128 tile, 256 threads
//   (4 waves), 8x8 micro-tile, BK=16. LDS = 2 x 4224-float buffers
//   (At[16][132]=2112 + Bs[16][128]=2048 + 64 slack) = 33792 B -> 4 blk/CU.
//   Grid 32x32 = 1024 blocks = 4 blk/CU x 4 waves = 16 waves/CU (4/SIMD).
//   __launch_bounds__(256,4) keeps VGPR <= 128 (acc 64 + ~30 overhead ~ 90)
//   so 4 waves/SIMD are actually resident.
//   Epilogue Ds[32][132] = 4224 = exactly buf0, disjoint from buf1 which
//   laggard waves may still read for tile 31 (31&1==1).
// ARITHMETIC BIT-IDENTICAL to rounds 6-15: each output = one ascending-k
// fmaf chain (t ascending, kk ascending, single accumulator); epilogue
// expression Phi + (Ds + b2) unchanged. absmax must stay exactly 0.203125.
// ---------------------------------------------------------------------------
__global__ __launch_bounds__(256, 4) void k2_gemm_gather(
    const float* __restrict__ h, const float* __restrict__ W2,
    const float* __restrict__ b2, const float* __restrict__ Phi,
    const int* __restrict__ idx, float* __restrict__ phi)
{
  // per buffer: At [16][132] = 2112 floats, Bs [16][128] = 2048, +64 slack
  __shared__ __align__(16) float smem[2 * 4224];   // 33792 B -> 4 blocks/CU

  const int tid = threadIdx.x;               // 0..255
  const int s0 = blockIdx.x * 128;           // 128 batch rows per block
  const int ig = blockIdx.y;                 // fermion row, 0..31
  const int n0 = ig * 128;
  const int tx = tid & 15;                   // col group: cols tx*4, 64+tx*4
  const int ty = tid >> 4;                   // row group 0..15: rows ty*8..+7
  const int kA = tid & 15;                   // A stage: kk (0..15)
  const int rbA = (tid >> 4) * 8;            // A stage: row block base (0..120)
  const int kB = tid >> 5;                   // B stage: k row (0..7)
  const int cB = (tid & 31) * 4;             // B stage: col*4

  float acc[8][8];
  #pragma unroll
  for (int i = 0; i < 8; ++i)
    #pragma unroll
    for (int u = 0; u < 8; ++u) acc[i][u] = 0.f;

  float  aReg[8];
  float4 bReg[2];

  // ---- prologue: stage tile 0 into buf0 ----
  #pragma unroll
  for (int u = 0; u < 2; ++u)
    #pragma unroll
    for (int i = 0; i < 4; ++i)
      aReg[u * 4 + i] = h[(size_t)(s0 + rbA + u * 4 + i) * H_N + kA];
  #pragma unroll
  for (int u = 0; u < 2; ++u)
    bReg[u] = *(const float4*)&W2[(size_t)(kB + 8 * u) * NFM + n0 + cB];
  #pragma unroll
  for (int u = 0; u < 2; ++u)
    *(float4*)&smem[kA * 132 + rbA + u * 4] =
        make_float4(aReg[4 * u], aReg[4 * u + 1], aReg[4 * u + 2], aReg[4 * u + 3]);
  #pragma unroll
  for (int u = 0; u < 2; ++u)
    *(float4*)&smem[2112 + (kB + 8 * u) * 128 + cB] = bReg[u];
  __syncthreads();

  #pragma unroll 1
  for (int t = 0; t < 32; ++t) {
    float* Atc = smem + (t & 1) * 4224;
    float* Bsc = Atc + 2112;
    float* Atn = smem + ((t + 1) & 1) * 4224;
    float* Bsn = Atn + 2112;

    // issue next tile's global loads (latency hides under compute)
    if (t < 31) {
      int k0n = (t + 1) * 16;
      #pragma unroll
      for (int u = 0; u < 2; ++u)
        #pragma unroll
        for (int i = 0; i < 4; ++i)
          aReg[u * 4 + i] = h[(size_t)(s0 + rbA + u * 4 + i) * H_N + k0n + kA];
      #pragma unroll
      for (int u = 0; u < 2; ++u)
        bReg[u] = *(const float4*)&W2[(size_t)(k0n + kB + 8 * u) * NFM + n0 + cB];
    }

    // compute tile t: 4 x ds_read_b128 + 64 fmaf per kk
    #pragma unroll 8
    for (int kk = 0; kk < 16; ++kk) {
      float4 a0 = *(const float4*)&Atc[kk * 132 + ty * 8];
      float4 a1 = *(const float4*)&Atc[kk * 132 + ty * 8 + 4];
      float4 b0 = *(const float4*)&Bsc[kk * 128 + tx * 4];
      float4 b1 = *(const float4*)&Bsc[kk * 128 + tx * 4 + 64];
      float a[8]  = {a0.x, a0.y, a0.z, a0.w, a1.x, a1.y, a1.z, a1.w};
      float bb[8] = {b0.x, b0.y, b0.z, b0.w, b1.x, b1.y, b1.z, b1.w};
      #pragma unroll
      for (int i = 0; i < 8; ++i)
        #pragma unroll
        for (int u = 0; u < 8; ++u)
          acc[i][u] = fmaf(a[i], bb[u], acc[i][u]);
    }

    // stage tile t+1 into the idle buffer; single barrier flips
    if (t < 31) {
      #pragma unroll
      for (int u = 0; u < 2; ++u)
        *(float4*)&Atn[kA * 132 + rbA + u * 4] =
            make_float4(aReg[4 * u], aReg[4 * u + 1], aReg[4 * u + 2], aReg[4 * u + 3]);
      #pragma unroll
      for (int u = 0; u < 2; ++u)
        *(float4*)&Bsn[(kB + 8 * u) * 128 + cB] = bReg[u];
      __syncthreads();
    }
  }

  // epilogue: 4 quarters of 32 rows through buf0's region (disjoint from
  // buf1, which laggard waves may still be reading for tile 31).
  // q compile-time (full unroll) so acc stays statically indexed (rule 20).
  float* Ds = smem;                          // [32][132] = 4224 floats = buf0
  #pragma unroll
  for (int q = 0; q < 4; ++q) {
    if ((ty >> 2) == q) {
      int r8 = (ty & 3) * 8;
      #pragma unroll
      for (int i = 0; i < 8; ++i) {
        *(float4*)&Ds[(r8 + i) * 132 + tx * 4] =
            make_float4(acc[i][0], acc[i][1], acc[i][2], acc[i][3]);
        *(float4*)&Ds[(r8 + i) * 132 + tx * 4 + 64] =
            make_float4(acc[i][4], acc[i][5], acc[i][6], acc[i][7]);
      }
    }
    __syncthreads();
    #pragma unroll
    for (int u = 0; u < 4; ++u) {
      int lin = u * 256 + tid;
      int r = lin >> 5, j = lin & 31;
      int b = s0 + q * 32 + r;
      int c = idx[b * F_N + j];
      float val = Phi[ig * M_N + c] + (Ds[r * 132 + c] + b2[n0 + c]);
      phi[(size_t)b * (F_N * F_N) + ig * F_N + j] = val;
    }
    __syncthreads();
  }
}

// ---------------------------------------------------------------------------
// Kernel 3: batched 32x32 fp32 LU replicating LAPACK sgetf2 exactly.
// Each matrix is owned by ONE wave working in its private LDS slice, so all
// cross-wave __syncthreads() are replaced with wave-local WAVE_SYNC()
// (s_waitcnt lgkmcnt(0)): the 4 waves per block run fully decoupled.
// Arithmetic sequence per matrix UNCHANGED from rounds 6-11.
// PLANAR complex output: out[0..B-1] = log|det|, out[B..2B-1] = arg(sign)
// ---------------------------------------------------------------------------
__global__ __launch_bounds__(256) void k3_det(
    const float* __restrict__ phi, float* __restrict__ out)
{
  __shared__ float A[4][32 * 33];
  const int w = threadIdx.x >> 6;
  const int lane = threadIdx.x & 63;
  const int b = blockIdx.x * 4 + w;
  float* Aw = A[w];

  #pragma unroll
  for (int u = 0; u < 16; ++u) {
    int lin = u * 64 + lane;
    Aw[(lin >> 5) * 33 + (lin & 31)] = phi[(size_t)b * 1024 + lin];
  }
  WAVE_SYNC();

  float logabs = 0.f;
  int negs = 0;
  for (int k = 0; k < 32; ++k) {
    // isamax over rows k..31 of column k (ties -> first index)
    float v = -1.f;
    int vi = lane;
    if (lane >= k && lane < 32) v = fabsf(Aw[lane * 33 + k]);
    #pragma unroll
    for (int off = 32; off > 0; off >>= 1) {
      float ov = __shfl_xor(v, off);
      int oi = __shfl_xor(vi, off);
      if (ov > v || (ov == v && oi < vi)) { v = ov; vi = oi; }
    }
    int p = vi;                          // uniform across the wave
    if (p != k) {
      negs ^= 1;
      if (lane < 32) {
        float tmp = Aw[k * 33 + lane];
        Aw[k * 33 + lane] = Aw[p * 33 + lane];
        Aw[p * 33 + lane] = tmp;
      }
    }
    WAVE_SYNC();
    float piv = Aw[k * 33 + k];
    if (piv < 0.f) negs ^= 1;
    logabs += logf(fabsf(piv));
    if (lane > k && lane < 32) {
      float l = Aw[lane * 33 + k];
      if (fabsf(piv) >= 1.17549435e-38f) l = l * (1.0f / piv);  // sscal path
      else                               l = l / piv;           // tiny pivot
      Aw[lane * 33 + k] = l;
    }
    WAVE_SYNC();
    if (lane > k && lane < 32) {
      int j = lane;
      float nukj = -Aw[k * 33 + j];
      for (int i = k + 1; i < 32; ++i)
        Aw[i * 33 + j] = fmaf(nukj, Aw[i * 33 + k], Aw[i * 33 + j]);
    }
    WAVE_SYNC();
  }

  if (lane == 0) {
    out[b]       = logabs;                                   // Re: log|det|
    out[B_N + b] = (negs & 1) ? 3.14159265358979f : 0.0f;    // Im: arg(sign)
  }
}

// ---------------------------------------------------------------------------
extern "C" void kernel_launch(void* const* d_in, const int* in_sizes, int n_in,
                              void* d_out, int out_size, void* d_ws, size_t ws_size,
                              hipStream_t stream) {
  const float* n   = (const float*)d_in[0];
  const float* Phi = (const float*)d_in[1];
  const float* W1  = (const float*)d_in[2];
  const float* b1  = (const float*)d_in[3];
  const float* W2  = (const float*)d_in[4];
  const float* b2  = (const float*)d_in[5];
  float* out = (float*)d_out;

  char* ws = (char*)d_ws;
  float* h_ws   = (float*)ws;                                   // 8 MB
  int*   idx_ws = (int*)(ws + (size_t)B_N * H_N * 4);           // 512 KB
  float* phi_ws = (float*)(ws + (size_t)B_N * H_N * 4
                              + (size_t)B_N * F_N * 4);         // 16 MB

  hipLaunchKernelGGL(k1_idx_h, dim3(B_N), dim3(256), 0, stream,
                     n, W1, b1, h_ws, idx_ws);
  hipLaunchKernelGGL(k2_gemm_gather, dim3(B_N / 128, F_N), dim3(256), 0, stream,
                     h_ws, W2, b2, Phi, idx_ws, phi_ws);
  hipLaunchKernelGGL(k3_det, dim3(B_N / 4), dim3(256), 0, stream,
                     phi_ws, out);
}

// Round 6
// 311.025 us; speedup vs baseline: 1.0584x; 1.0584x over previous
//
#include <hip/hip_runtime.h>
#include <hip/hip_bf16.h>
#include <math.h>

#define B_N 4096
#define M_N 128
#define F_N 32
#define H_N 512
#define NFM 4096   // F*M

// wave-local LDS sync: all lanes of a wave run in lockstep, so a waitcnt on
// outstanding LDS ops makes prior cross-lane LDS writes visible to reads.
#define WAVE_SYNC() do { \
  asm volatile("s_waitcnt lgkmcnt(0)" ::: "memory"); \
  __builtin_amdgcn_sched_barrier(0); \
} while (0)

// ---------------------------------------------------------------------------
// Kernel 1: occupied-index extraction (wave ballot, parallel) + hidden layer
//   h[b,:] = tanhf( sum_j W1[idx_j,:] + b1 )   (ascending-j chain, fp32)
// ---------------------------------------------------------------------------
__global__ __launch_bounds__(256) void k1_idx_h(
    const float* __restrict__ n, const float* __restrict__ W1,
    const float* __restrict__ b1, float* __restrict__ h_ws,
    int* __restrict__ idx_ws)
{
  __shared__ int s_idx[F_N];
  __shared__ int s_cnt0;
  const int b = blockIdx.x;
  const int t = threadIdx.x;

  bool p = false;
  int before = 0;
  if (t < 128) {
    float v = n[(size_t)b * M_N + t];
    p = v > 0.5f;
    unsigned long long m = __ballot(p);
    int lane = t & 63;
    before = __popcll(m & ((1ull << lane) - 1ull));
    if (t < 64) {
      if (lane == 0) s_cnt0 = __popcll(m);
      if (p) s_idx[before] = t;          // ascending within wave 0
    }
  }
  __syncthreads();
  if (t >= 64 && t < 128 && p) s_idx[s_cnt0 + before] = t;
  __syncthreads();

  if (t < F_N) idx_ws[b * F_N + t] = s_idx[t];

  #pragma unroll
  for (int cc = 0; cc < 2; ++cc) {
    int c = t + cc * 256;
    float acc = 0.0f;
    #pragma unroll
    for (int j = 0; j < F_N; ++j)
      acc += W1[(size_t)s_idx[j] * H_N + c];
    acc += b1[c];                        // b1 = zeros: exact
    h_ws[(size_t)b * H_N + c] = tanhf(acc);
  }
}

// ---------------------------------------------------------------------------
// Kernel 2 (ROUND 17): tiled fp32 GEMM  bf = h @ W2.
// ROUND 16 post-mortem: __launch_bounds__(256,4) made the compiler squeeze
//   VGPR to 64 (= the accumulator alone) -> ~30 live values spilled to
//   scratch (WRITE_SIZE 20->263 MB, FETCH 45->160 MB). Occupancy DID rise
//   19->35% and nearly paid for the spill (252 vs 237 us) — the occupancy
//   lever is real; the register coercion was the bug.
// ROUND 17 = round 16 minus the min-waves bound (single-variable change):
//   plain __launch_bounds__(256). Natural allocation for this structure is
//   ~85-100 VGPR (round 0 measured 88 with a bigger BK=32 prefetch), i.e.
//   the 65..128 bracket -> 4 waves/SIMD uncoerced. 128x128 tile, 256
//   threads, 8x8 micro-tile, BK=16, LDS 2 x 4224 floats = 33792 B ->
//   4 blocks/CU; grid 32x32 = 1024 = 4 blocks/CU -> 16 waves/CU.
//   Epilogue Ds[32][132] = 4224 = exactly buf0, disjoint from buf1 which
//   laggard waves may still read for tile 31 (31&1==1).
// ARITHMETIC BIT-IDENTICAL to rounds 6-16: each output = one ascending-k
// fmaf chain (t ascending, kk ascending, single accumulator); epilogue
// expression Phi + (Ds + b2) unchanged. absmax must stay exactly 0.203125.
// ---------------------------------------------------------------------------
__global__ __launch_bounds__(256) void k2_gemm_gather(
    const float* __restrict__ h, const float* __restrict__ W2,
    const float* __restrict__ b2, const float* __restrict__ Phi,
    const int* __restrict__ idx, float* __restrict__ phi)
{
  // per buffer: At [16][132] = 2112 floats, Bs [16][128] = 2048, +64 slack
  __shared__ __align__(16) float smem[2 * 4224];   // 33792 B -> 4 blocks/CU

  const int tid = threadIdx.x;               // 0..255
  const int s0 = blockIdx.x * 128;           // 128 batch rows per block
  const int ig = blockIdx.y;                 // fermion row, 0..31
  const int n0 = ig * 128;
  const int tx = tid & 15;                   // col group: cols tx*4, 64+tx*4
  const int ty = tid >> 4;                   // row group 0..15: rows ty*8..+7
  const int kA = tid & 15;                   // A stage: kk (0..15)
  const int rbA = (tid >> 4) * 8;            // A stage: row block base (0..120)
  const int kB = tid >> 5;                   // B stage: k row (0..7)
  const int cB = (tid & 31) * 4;             // B stage: col*4

  float acc[8][8];
  #pragma unroll
  for (int i = 0; i < 8; ++i)
    #pragma unroll
    for (int u = 0; u < 8; ++u) acc[i][u] = 0.f;

  float  aReg[8];
  float4 bReg[2];

  // ---- prologue: stage tile 0 into buf0 ----
  #pragma unroll
  for (int u = 0; u < 2; ++u)
    #pragma unroll
    for (int i = 0; i < 4; ++i)
      aReg[u * 4 + i] = h[(size_t)(s0 + rbA + u * 4 + i) * H_N + kA];
  #pragma unroll
  for (int u = 0; u < 2; ++u)
    bReg[u] = *(const float4*)&W2[(size_t)(kB + 8 * u) * NFM + n0 + cB];
  #pragma unroll
  for (int u = 0; u < 2; ++u)
    *(float4*)&smem[kA * 132 + rbA + u * 4] =
        make_float4(aReg[4 * u], aReg[4 * u + 1], aReg[4 * u + 2], aReg[4 * u + 3]);
  #pragma unroll
  for (int u = 0; u < 2; ++u)
    *(float4*)&smem[2112 + (kB + 8 * u) * 128 + cB] = bReg[u];
  __syncthreads();

  #pragma unroll 1
  for (int t = 0; t < 32; ++t) {
    float* Atc = smem + (t & 1) * 4224;
    float* Bsc = Atc + 2112;
    float* Atn = smem + ((t + 1) & 1) * 4224;
    float* Bsn = Atn + 2112;

    // issue next tile's global loads (latency hides under compute)
    if (t < 31) {
      int k0n = (t + 1) * 16;
      #pragma unroll
      for (int u = 0; u < 2; ++u)
        #pragma unroll
        for (int i = 0; i < 4; ++i)
          aReg[u * 4 + i] = h[(size_t)(s0 + rbA + u * 4 + i) * H_N + k0n + kA];
      #pragma unroll
      for (int u = 0; u < 2; ++u)
        bReg[u] = *(const float4*)&W2[(size_t)(k0n + kB + 8 * u) * NFM + n0 + cB];
    }

    // compute tile t: 4 x ds_read_b128 + 64 fmaf per kk
    #pragma unroll 8
    for (int kk = 0; kk < 16; ++kk) {
      float4 a0 = *(const float4*)&Atc[kk * 132 + ty * 8];
      float4 a1 = *(const float4*)&Atc[kk * 132 + ty * 8 + 4];
      float4 b0 = *(const float4*)&Bsc[kk * 128 + tx * 4];
      float4 b1 = *(const float4*)&Bsc[kk * 128 + tx * 4 + 64];
      float a[8]  = {a0.x, a0.y, a0.z, a0.w, a1.x, a1.y, a1.z, a1.w};
      float bb[8] = {b0.x, b0.y, b0.z, b0.w, b1.x, b1.y, b1.z, b1.w};
      #pragma unroll
      for (int i = 0; i < 8; ++i)
        #pragma unroll
        for (int u = 0; u < 8; ++u)
          acc[i][u] = fmaf(a[i], bb[u], acc[i][u]);
    }

    // stage tile t+1 into the idle buffer; single barrier flips
    if (t < 31) {
      #pragma unroll
      for (int u = 0; u < 2; ++u)
        *(float4*)&Atn[kA * 132 + rbA + u * 4] =
            make_float4(aReg[4 * u], aReg[4 * u + 1], aReg[4 * u + 2], aReg[4 * u + 3]);
      #pragma unroll
      for (int u = 0; u < 2; ++u)
        *(float4*)&Bsn[(kB + 8 * u) * 128 + cB] = bReg[u];
      __syncthreads();
    }
  }

  // epilogue: 4 quarters of 32 rows through buf0's region (disjoint from
  // buf1, which laggard waves may still be reading for tile 31).
  // q compile-time (full unroll) so acc stays statically indexed (rule 20).
  float* Ds = smem;                          // [32][132] = 4224 floats = buf0
  #pragma unroll
  for (int q = 0; q < 4; ++q) {
    if ((ty >> 2) == q) {
      int r8 = (ty & 3) * 8;
      #pragma unroll
      for (int i = 0; i < 8; ++i) {
        *(float4*)&Ds[(r8 + i) * 132 + tx * 4] =
            make_float4(acc[i][0], acc[i][1], acc[i][2], acc[i][3]);
        *(float4*)&Ds[(r8 + i) * 132 + tx * 4 + 64] =
            make_float4(acc[i][4], acc[i][5], acc[i][6], acc[i][7]);
      }
    }
    __syncthreads();
    #pragma unroll
    for (int u = 0; u < 4; ++u) {
      int lin = u * 256 + tid;
      int r = lin >> 5, j = lin & 31;
      int b = s0 + q * 32 + r;
      int c = idx[b * F_N + j];
      float val = Phi[ig * M_N + c] + (Ds[r * 132 + c] + b2[n0 + c]);
      phi[(size_t)b * (F_N * F_N) + ig * F_N + j] = val;
    }
    __syncthreads();
  }
}

// ---------------------------------------------------------------------------
// Kernel 3: batched 32x32 fp32 LU replicating LAPACK sgetf2 exactly.
// Each matrix is owned by ONE wave working in its private LDS slice, so all
// cross-wave __syncthreads() are replaced with wave-local WAVE_SYNC()
// (s_waitcnt lgkmcnt(0)): the 4 waves per block run fully decoupled.
// Arithmetic sequence per matrix UNCHANGED from rounds 6-11.
// PLANAR complex output: out[0..B-1] = log|det|, out[B..2B-1] = arg(sign)
// ---------------------------------------------------------------------------
__global__ __launch_bounds__(256) void k3_det(
    const float* __restrict__ phi, float* __restrict__ out)
{
  __shared__ float A[4][32 * 33];
  const int w = threadIdx.x >> 6;
  const int lane = threadIdx.x & 63;
  const int b = blockIdx.x * 4 + w;
  float* Aw = A[w];

  #pragma unroll
  for (int u = 0; u < 16; ++u) {
    int lin = u * 64 + lane;
    Aw[(lin >> 5) * 33 + (lin & 31)] = phi[(size_t)b * 1024 + lin];
  }
  WAVE_SYNC();

  float logabs = 0.f;
  int negs = 0;
  for (int k = 0; k < 32; ++k) {
    // isamax over rows k..31 of column k (ties -> first index)
    float v = -1.f;
    int vi = lane;
    if (lane >= k && lane < 32) v = fabsf(Aw[lane * 33 + k]);
    #pragma unroll
    for (int off = 32; off > 0; off >>= 1) {
      float ov = __shfl_xor(v, off);
      int oi = __shfl_xor(vi, off);
      if (ov > v || (ov == v && oi < vi)) { v = ov; vi = oi; }
    }
    int p = vi;                          // uniform across the wave
    if (p != k) {
      negs ^= 1;
      if (lane < 32) {
        float tmp = Aw[k * 33 + lane];
        Aw[k * 33 + lane] = Aw[p * 33 + lane];
        Aw[p * 33 + lane] = tmp;
      }
    }
    WAVE_SYNC();
    float piv = Aw[k * 33 + k];
    if (piv < 0.f) negs ^= 1;
    logabs += logf(fabsf(piv));
    if (lane > k && lane < 32) {
      float l = Aw[lane * 33 + k];
      if (fabsf(piv) >= 1.17549435e-38f) l = l * (1.0f / piv);  // sscal path
      else                               l = l / piv;           // tiny pivot
      Aw[lane * 33 + k] = l;
    }
    WAVE_SYNC();
    if (lane > k && lane < 32) {
      int j = lane;
      float nukj = -Aw[k * 33 + j];
      for (int i = k + 1; i < 32; ++i)
        Aw[i * 33 + j] = fmaf(nukj, Aw[i * 33 + k], Aw[i * 33 + j]);
    }
    WAVE_SYNC();
  }

  if (lane == 0) {
    out[b]       = logabs;                                   // Re: log|det|
    out[B_N + b] = (negs & 1) ? 3.14159265358979f : 0.0f;    // Im: arg(sign)
  }
}

// ---------------------------------------------------------------------------
extern "C" void kernel_launch(void* const* d_in, const int* in_sizes, int n_in,
                              void* d_out, int out_size, void* d_ws, size_t ws_size,
                              hipStream_t stream) {
  const float* n   = (const float*)d_in[0];
  const float* Phi = (const float*)d_in[1];
  const float* W1  = (const float*)d_in[2];
  const float* b1  = (const float*)d_in[3];
  const float* W2  = (const float*)d_in[4];
  const float* b2  = (const float*)d_in[5];
  float* out = (float*)d_out;

  char* ws = (char*)d_ws;
  float* h_ws   = (float*)ws;                                   // 8 MB
  int*   idx_ws = (int*)(ws + (size_t)B_N * H_N * 4);           // 512 KB
  float* phi_ws = (float*)(ws + (size_t)B_N * H_N * 4
                              + (size_t)B_N * F_N * 4);         // 16 MB

  hipLaunchKernelGGL(k1_idx_h, dim3(B_N), dim3(256), 0, stream,
                     n, W1, b1, h_ws, idx_ws);
  hipLaunchKernelGGL(k2_gemm_gather, dim3(B_N / 128, F_N), dim3(256), 0, stream,
                     h_ws, W2, b2, Phi, idx_ws, phi_ws);
  hipLaunchKernelGGL(k3_det, dim3(B_N / 4), dim3(256), 0, stream,
                     phi_ws, out);
}